// Round 16
// baseline (224.294 us; speedup 1.0000x reference)
//
#include <hip/hip_runtime.h>
#include <hip/hip_fp16.h>
#include <math.h>

#define NPTS 262144
#define PLANE_ELEMS 16777216u   // 256*256*256

typedef __attribute__((ext_vector_type(4))) float f4;
typedef __attribute__((ext_vector_type(4))) unsigned int u4;

// ws layout (bytes):
//   [0, 96 MB)        : fp16 transposed planes (3 x 32 MB), layout [hw][c=256]
//   +3.1 MB           : idx u32[3][NPTS]  (sorted pos -> original n)
//   +16.8 MB          : partial fp16[2][NPTS][16]  (planes 0,1 only)
//   +0.75 MB          : hist unsigned[3][65536]
#define OFF_IDX      (3ull * PLANE_ELEMS * 2ull)
#define OFF_PARTIAL  (OFF_IDX + (size_t)3 * NPTS * 4)
#define OFF_HIST     (OFF_PARTIAL + (size_t)2 * NPTS * 16 * 2)
#define WS_NEED      (OFF_HIST + (size_t)3 * 65536 * 4)

__device__ __forceinline__ void plane_xy(int p, float c0, float c1, float c2,
                                         float& gx, float& gy, float& ax) {
  if (p == 0)      { gx = c1; gy = c2; ax = c0; }
  else if (p == 1) { gx = c0; gy = c2; ax = c1; }
  else             { gx = c0; gy = c1; ax = c2; }
}

__device__ __forceinline__ int cell_of(float g) {
  float i = (g + 1.f) * 0.5f * 255.f;
  int x0 = (int)floorf(i);
  return x0 < 0 ? 0 : (x0 > 255 ? 255 : x0);
}

// ---------------------------------------------------------------------------
// Trans helpers (R10-verified).
// ---------------------------------------------------------------------------
__device__ __forceinline__ void trans_load(const float* __restrict__ src,
                                           unsigned c0, unsigned hw0, int tid,
                                           f4 (&va)[4], f4 (&vb)[4]) {
#pragma unroll
  for (int j = 0; j < 4; ++j) {
    int idx = j * 256 + tid;
    int rp = idx >> 5;
    int q = idx & 31;
    const f4* base = (const f4*)(src + (size_t)(c0 + 2 * rp) * 65536u + hw0 + 4 * q);
    va[j] = __builtin_nontemporal_load(base);
    vb[j] = __builtin_nontemporal_load(base + 16384);
  }
}

__device__ __forceinline__ void trans_proc(unsigned* tile, __half* dst,
                                           unsigned c0, unsigned hw0, int tid,
                                           f4 (&va)[4], f4 (&vb)[4]) {
#pragma unroll
  for (int j = 0; j < 4; ++j) {
    int idx = j * 256 + tid;
    int rp = idx >> 5;
    int q = idx & 31;
#pragma unroll
    for (int k = 0; k < 4; ++k) {
      int hw = 4 * q + k;
      __half2 h = __floats2half2_rn(va[j][k], vb[j][k]);
      tile[hw * 36 + (rp ^ (hw >> 3))] = *(unsigned*)&h;
    }
  }
  __syncthreads();
  int seg = tid & 7;
#pragma unroll
  for (int jj = 0; jj < 4; ++jj) {
    int hw = jj * 32 + (tid >> 3);
    int s = hw >> 3;
    u4 v = *(const u4*)(tile + hw * 36 + 4 * ((seg ^ (s >> 2)) & 7));
    u4 o;
    switch (s & 3) {
      case 0: o = v; break;
      case 1: o = u4{v.y, v.x, v.w, v.z}; break;
      case 2: o = u4{v.z, v.w, v.x, v.y}; break;
      default: o = u4{v.w, v.z, v.y, v.x}; break;
    }
    *(u4*)((char*)dst + ((size_t)(hw0 + hw) * 256u + c0) * 2u + seg * 16u) = o;
  }
  __syncthreads();
}

__device__ __forceinline__ void trans_unit(const float* __restrict__ src,
                                           __half* __restrict__ dst,
                                           unsigned hwbase, unsigned c0, int tid,
                                           unsigned* tile) {
  f4 vaA[4], vbA[4], vaB[4], vbB[4];
  trans_load(src, c0, hwbase, tid, vaA, vbA);
  trans_load(src, c0, hwbase + 128u, tid, vaB, vbB);
  trans_proc(tile, dst, c0, hwbase, tid, vaA, vbA);
  trans_load(src, c0, hwbase + 256u, tid, vaA, vbA);
  trans_proc(tile, dst, c0, hwbase + 128u, tid, vaB, vbB);
  trans_load(src, c0, hwbase + 384u, tid, vaB, vbB);
  trans_proc(tile, dst, c0, hwbase + 256u, tid, vaA, vbA);
  trans_proc(tile, dst, c0, hwbase + 384u, tid, vaB, vbB);
}

__device__ __forceinline__ void hist_point(
    int p, int n, const float* __restrict__ inputs, unsigned* __restrict__ hist) {
  float c0 = inputs[n * 3 + 0], c1 = inputs[n * 3 + 1], c2 = inputs[n * 3 + 2];
  float gx, gy, ax;
  plane_xy(p, c0, c1, c2, gx, gy, ax);
  int key = (cell_of(gy) << 8) | cell_of(gx);
  atomicAdd(&hist[p * 65536 + key], 1u);
}

__device__ __forceinline__ void scat_point(
    int p, int n, const float* __restrict__ inputs,
    unsigned* __restrict__ hist, unsigned* __restrict__ idx) {
  float c0 = inputs[n * 3 + 0], c1 = inputs[n * 3 + 1], c2 = inputs[n * 3 + 2];
  float gx, gy, ax;
  plane_xy(p, c0, c1, c2, gx, gy, ax);
  int key = (cell_of(gy) << 8) | cell_of(gx);
  unsigned pos = atomicAdd(&hist[p * 65536 + key], 1u);
  idx[(size_t)p * NPTS + pos] = (unsigned)n;
}

// ---------------------------------------------------------------------------
// Sample body (R12-verified). FINAL=1 fuses the reduce (R15).
// ---------------------------------------------------------------------------
template <int FINAL>
__device__ __forceinline__ void samp_point(
    int p, int slot, int t, const unsigned* __restrict__ idx,
    const float* __restrict__ inputs, const __half* __restrict__ T,
    __half* __restrict__ partial, float* __restrict__ out) {
  unsigned n = idx[(size_t)p * NPTS + slot];
  float c0 = inputs[n * 3 + 0], c1 = inputs[n * 3 + 1], c2 = inputs[n * 3 + 2];
  float gx, gy, ax;
  plane_xy(p, c0, c1, c2, gx, gy, ax);

  float ix = (gx + 1.f) * 0.5f * 255.f;
  float iy = (gy + 1.f) * 0.5f * 255.f;
  float x0f = floorf(ix), y0f = floorf(iy);
  float wx = ix - x0f, wy = iy - y0f;
  int x0 = (int)x0f; x0 = x0 < 0 ? 0 : (x0 > 255 ? 255 : x0);
  int y0 = (int)y0f; y0 = y0 < 0 ? 0 : (y0 > 255 ? 255 : y0);
  int x1 = x0 + 1 > 255 ? 255 : x0 + 1;
  int y1 = y0 + 1 > 255 ? 255 : y0 + 1;
  float w00 = (1.f - wx) * (1.f - wy);
  float w01 = wx * (1.f - wy);
  float w10 = (1.f - wx) * wy;
  float w11 = wx * wy;

  const __half* __restrict__ P = T + (size_t)p * PLANE_ELEMS;
  int r00 = (y0 * 256 + x0) * 256, r01 = (y0 * 256 + x1) * 256;
  int r10 = (y1 * 256 + x0) * 256, r11 = (y1 * 256 + x1) * 256;
  int ore = t * 16;
  int oim = 128 + t * 16;

  f4 a0 = *(const f4*)(P + r00 + ore),     a1 = *(const f4*)(P + r00 + ore + 8);
  f4 a2 = *(const f4*)(P + r00 + oim),     a3 = *(const f4*)(P + r00 + oim + 8);
  f4 b0 = *(const f4*)(P + r01 + ore),     b1 = *(const f4*)(P + r01 + ore + 8);
  f4 b2 = *(const f4*)(P + r01 + oim),     b3 = *(const f4*)(P + r01 + oim + 8);
  f4 c0v = *(const f4*)(P + r10 + ore),    c1v = *(const f4*)(P + r10 + ore + 8);
  f4 c2v = *(const f4*)(P + r10 + oim),    c3v = *(const f4*)(P + r10 + oim + 8);
  f4 d0 = *(const f4*)(P + r11 + ore),     d1 = *(const f4*)(P + r11 + ore + 8);
  f4 d2 = *(const f4*)(P + r11 + oim),     d3 = *(const f4*)(P + r11 + oim + 8);

  __half2 hw00 = __float2half2_rn(w00), hw01 = __float2half2_rn(w01);
  __half2 hw10 = __float2half2_rn(w10), hw11 = __float2half2_rn(w11);

  __half2 bre[8], bim[8];
#pragma unroll
  for (int q = 0; q < 4; ++q) {
    __half2 v;
    v = __hmul2(((const __half2*)&a0)[q], hw00);
    v = __hfma2(((const __half2*)&b0)[q],  hw01, v);
    v = __hfma2(((const __half2*)&c0v)[q], hw10, v);
    bre[q] = __hfma2(((const __half2*)&d0)[q], hw11, v);

    v = __hmul2(((const __half2*)&a1)[q], hw00);
    v = __hfma2(((const __half2*)&b1)[q],  hw01, v);
    v = __hfma2(((const __half2*)&c1v)[q], hw10, v);
    bre[q + 4] = __hfma2(((const __half2*)&d1)[q], hw11, v);

    v = __hmul2(((const __half2*)&a2)[q], hw00);
    v = __hfma2(((const __half2*)&b2)[q],  hw01, v);
    v = __hfma2(((const __half2*)&c2v)[q], hw10, v);
    bim[q] = __hfma2(((const __half2*)&d2)[q], hw11, v);

    v = __hmul2(((const __half2*)&a3)[q], hw00);
    v = __hfma2(((const __half2*)&b3)[q],  hw01, v);
    v = __hfma2(((const __half2*)&c3v)[q], hw10, v);
    bim[q + 4] = __hfma2(((const __half2*)&d3)[q], hw11, v);
  }

  float fre[16], fim[16];
#pragma unroll
  for (int q = 0; q < 8; ++q) {
    float2 vr = __half22float2(bre[q]);
    float2 vi = __half22float2(bim[q]);
    fre[2 * q] = vr.x; fre[2 * q + 1] = vr.y;
    fim[2 * q] = vi.x; fim[2 * q + 1] = vi.y;
  }

  float cs = (ax + 1.f) * 0.5f * 255.f;
  float th = 6.283185307179586f * cs * (1.f / 256.f);
  float s, c;
  __sincosf(th, &s, &c);
  float aR0 = fre[0], aR1 = fre[8];
  float aI0 = 0.f,    aI1 = 0.f;
#pragma unroll
  for (int r = 1; r < 8; ++r) {
    aR0 += fre[r] * c;     aR1 += fre[8 + r] * c;
    aI0 += fim[r] * s;     aI1 += fim[8 + r] * s;
    if (r < 7) {
      float c2 = c + c;
      float cn = c2 * c - 1.f;
      s = c2 * s;
      c = cn;
    }
  }

  if (FINAL) {
    const size_t PS = (size_t)NPTS * 16;
    float2 p0 = __half22float2(*(const __half2*)(partial + (size_t)n * 16 + 2 * t));
    float2 p1 = __half22float2(*(const __half2*)(partial + PS + (size_t)n * 16 + 2 * t));
    float2 o;
    o.x = (aR0 - aI0) + p0.x + p1.x;
    o.y = (aR1 - aI1) + p0.y + p1.y;
    *(float2*)(out + (size_t)n * 16 + 2 * t) = o;
  } else {
    *(__half2*)(partial + ((size_t)p * NPTS + n) * 16 + 2 * t) =
        __floats2half2_rn(aR0 - aI0, aR1 - aI1);
  }
}

// ---------------------------------------------------------------------------
// fat1a: trans(plane 0) ∥ hist(plane 0). grid 768: bx%3<2 -> trans (512
// units), bx%3==2 -> hist (256 blocks x 4 items).
// ---------------------------------------------------------------------------
__global__ __launch_bounds__(256) void PREFFFT_fat1a_k(
    const float* __restrict__ Pu, __half* __restrict__ dst0,
    const float* __restrict__ inputs, unsigned* __restrict__ hist) {
  __shared__ unsigned tile[128 * 36];
  const int bx = blockIdx.x;
  const int tid = threadIdx.x;
  if ((bx % 3) != 2) {
    int ti = (bx / 3) * 2 + (bx % 3);   // 0..511 (plane 0)
    int by = ti >> 7;
    int bxx = ti & 127;
    trans_unit(Pu, dst0, bxx * 512u, by * 64u, tid, tile);
  } else {
    int hb = bx / 3;                    // 0..255
#pragma unroll
    for (int it = 0; it < 4; ++it) {
      int n = hb * 1024 + it * 256 + tid;   // < 262144
      hist_point(0, n, inputs, hist);
    }
  }
}

// ---------------------------------------------------------------------------
// fat1b: trans(planes 1,2) ∥ hist(planes 1,2) ∥ scat(plane 0). grid 2560:
// bx%5<2 -> trans (1024 units), ==2 -> hist (512 blocks x 4), >=3 -> scat
// (1024 blocks x 1). scat p0 needs scanA done; hist p1/p2 bins are untouched
// by scat (disjoint ranges).
// ---------------------------------------------------------------------------
__global__ __launch_bounds__(256) void PREFFFT_fat1b_k(
    const float* __restrict__ Pv, const float* __restrict__ Pw,
    __half* __restrict__ dst0, const float* __restrict__ inputs,
    unsigned* __restrict__ hist, unsigned* __restrict__ idx) {
  __shared__ unsigned tile[128 * 36];
  const int bx = blockIdx.x;
  const int tid = threadIdx.x;
  int r = bx % 5, q5 = bx / 5;
  if (r < 2) {
    int u = q5 * 2 + r;                 // 0..1023
    int bz = 1 + (u >> 9);              // 1 or 2
    int rem = u & 511;
    int by = rem >> 7;
    int bxx = rem & 127;
    const float* src = bz == 1 ? Pv : Pw;
    trans_unit(src, dst0 + (size_t)bz * PLANE_ELEMS, bxx * 512u, by * 64u,
               tid, tile);
  } else if (r == 2) {
    int hb = q5;                        // 0..511
#pragma unroll
    for (int it = 0; it < 4; ++it) {
      int item = hb * 1024 + it * 256 + tid;   // < 524288
      int n = item & (NPTS - 1);
      int p = 1 + (item >> 18);                // 1 or 2
      hist_point(p, n, inputs, hist);
    }
  } else {
    int sb = q5 * 2 + (r - 3);          // 0..1023
    int n = sb * 256 + tid;
    scat_point(0, n, inputs, hist, idx);
  }
}

// ---------------------------------------------------------------------------
// Scan: exclusive prefix over 65536 bins; one block per plane, pbase offset.
// ---------------------------------------------------------------------------
__global__ __launch_bounds__(1024) void PREFFFT_scan_k(unsigned* __restrict__ hist,
                                                       int pbase) {
  __shared__ unsigned part[1024];
  unsigned* h = hist + (size_t)(pbase + blockIdx.x) * 65536;
  int t = threadIdx.x;
  unsigned s = 0;
#pragma unroll 8
  for (int i = 0; i < 64; ++i) s += h[t * 64 + i];
  part[t] = s;
  __syncthreads();
  for (int off = 1; off < 1024; off <<= 1) {
    unsigned v = (t >= off) ? part[t - off] : 0u;
    __syncthreads();
    part[t] += v;
    __syncthreads();
  }
  unsigned run = (t == 0) ? 0u : part[t - 1];
#pragma unroll 8
  for (int i = 0; i < 64; ++i) {
    unsigned c = h[t * 64 + i];
    h[t * 64 + i] = run;
    run += c;
  }
}

// ---------------------------------------------------------------------------
// Fat pipeline kernel: blocks [0,1024) = scat(plane sp+1) — dispatched first,
// latency hides under the 8192 samp(plane sp) blocks [1024, 9216).
// ---------------------------------------------------------------------------
__global__ __launch_bounds__(256) void PREFFFT_fat2_k(
    unsigned* __restrict__ idx, const float* __restrict__ inputs,
    const __half* __restrict__ T, __half* __restrict__ partial,
    unsigned* __restrict__ hist, int sp) {
  int bx = blockIdx.x;
  if (bx < 1024) {
    int n = bx * 256 + threadIdx.x;
    scat_point(sp + 1, n, inputs, hist, idx);
  } else {
    int b = bx - 1024;                        // 0..8191
    int lbx = (b & 7) * 1024 + (b >> 3);      // XCD-contiguous chunks
    int slot = lbx * 32 + ((int)threadIdx.x >> 3);
    samp_point<0>(sp, slot, threadIdx.x & 7, idx, inputs, T, partial, nullptr);
  }
}

// ---------------------------------------------------------------------------
// Final fused pass: samp(plane 2) + reduce(partials 0,1) -> f32 out. grid 8192.
// ---------------------------------------------------------------------------
__global__ __launch_bounds__(256) void PREFFFT_samp2out_k(
    const unsigned* __restrict__ idx, const float* __restrict__ inputs,
    const __half* __restrict__ T, __half* __restrict__ partial,
    float* __restrict__ out) {
  int b = blockIdx.x;
  int lbx = (b & 7) * 1024 + (b >> 3);
  int slot = lbx * 32 + ((int)threadIdx.x >> 3);
  samp_point<1>(2, slot, threadIdx.x & 7, idx, inputs, T, partial, out);
}

// ---------------------------------------------------------------------------
// Fallback (ws too small): original (C,H,W) fp32 direct, slow but correct.
// ---------------------------------------------------------------------------
__global__ __launch_bounds__(256) void PREFFFT_fallback_k(
    const float* __restrict__ inputs, const float* __restrict__ Tu,
    const float* __restrict__ Tv, const float* __restrict__ Tw,
    float* __restrict__ out) {
  int gtid = blockIdx.x * 256 + threadIdx.x;
  int n = gtid >> 5;
  int t = threadIdx.x & 31;
  const bool is_re = t < 16;
  float c0 = inputs[n * 3 + 0], c1 = inputs[n * 3 + 1], c2 = inputs[n * 3 + 2];
  const float* PL[3] = {Tu, Tv, Tw};
  float acc = 0.f;
#pragma unroll
  for (int p = 0; p < 3; ++p) {
    float gx, gy, ax;
    plane_xy(p, c0, c1, c2, gx, gy, ax);
    float ix = (gx + 1.f) * 0.5f * 255.f;
    float iy = (gy + 1.f) * 0.5f * 255.f;
    float x0f = floorf(ix), y0f = floorf(iy);
    float wx = ix - x0f, wy = iy - y0f;
    int x0 = (int)x0f; x0 = x0 < 0 ? 0 : (x0 > 255 ? 255 : x0);
    int y0 = (int)y0f; y0 = y0 < 0 ? 0 : (y0 > 255 ? 255 : y0);
    int x1 = x0 + 1 > 255 ? 255 : x0 + 1;
    int y1 = y0 + 1 > 255 ? 255 : y0 + 1;
    float w00 = (1.f - wx) * (1.f - wy), w01 = wx * (1.f - wy);
    float w10 = (1.f - wx) * wy, w11 = wx * wy;
    int i00 = y0 * 256 + x0, i01 = y0 * 256 + x1;
    int i10 = y1 * 256 + x0, i11 = y1 * 256 + x1;
    float b[8];
#pragma unroll
    for (int j = 0; j < 8; ++j) {
      const float* base = PL[p] + (size_t)(t * 8 + j) * 65536u;
      b[j] = w00 * base[i00] + w01 * base[i01] + w10 * base[i10] + w11 * base[i11];
    }
    float csv = (ax + 1.f) * 0.5f * 255.f;
    float theta1 = 6.283185307179586f * csv * (1.f / 256.f);
    float partial = is_re ? b[0] : 0.f;
#pragma unroll
    for (int r = 1; r < 8; ++r) {
      float thr = theta1 * (float)(1 << (r - 1));
      float s, c;
      __sincosf(thr, &s, &c);
      partial += b[r] * (is_re ? c : s);
    }
    float other = __shfl_xor(partial, 16);
    acc += partial - other;
  }
  if (is_re) out[n * 16 + t] = acc;
}

extern "C" void kernel_launch(void* const* d_in, const int* in_sizes, int n_in,
                              void* d_out, int out_size, void* d_ws, size_t ws_size,
                              hipStream_t stream) {
  const float* inputs = (const float*)d_in[0];
  const float* Pu = (const float*)d_in[1];
  const float* Pv = (const float*)d_in[2];
  const float* Pw = (const float*)d_in[3];
  float* out = (float*)d_out;

  if (ws_size >= WS_NEED) {
    char* ws = (char*)d_ws;
    __half*   T       = (__half*)ws;
    unsigned* idx     = (unsigned*)(ws + OFF_IDX);
    __half*   partial = (__half*)(ws + OFF_PARTIAL);
    unsigned* hist    = (unsigned*)(ws + OFF_HIST);

    hipMemsetAsync(hist, 0, (size_t)3 * 65536 * 4, stream);
    PREFFFT_fat1a_k<<<768, 256, 0, stream>>>(Pu, T, inputs, hist);
    PREFFFT_scan_k<<<1, 1024, 0, stream>>>(hist, 0);
    PREFFFT_fat1b_k<<<2560, 256, 0, stream>>>(Pv, Pw, T, inputs, hist, idx);
    PREFFFT_scan_k<<<2, 1024, 0, stream>>>(hist, 1);
    PREFFFT_fat2_k<<<9216, 256, 0, stream>>>(idx, inputs, T, partial, hist, 0);
    PREFFFT_fat2_k<<<9216, 256, 0, stream>>>(idx, inputs, T, partial, hist, 1);
    PREFFFT_samp2out_k<<<8192, 256, 0, stream>>>(idx, inputs, T, partial, out);
  } else {
    PREFFFT_fallback_k<<<NPTS / 8, 256, 0, stream>>>(inputs, Pu, Pv, Pw, out);
  }
}

// Round 17
// 217.230 us; speedup vs baseline: 1.0325x; 1.0325x over previous
//
#include <hip/hip_runtime.h>
#include <hip/hip_fp16.h>
#include <math.h>

#define NPTS 262144
#define PLANE_ELEMS 16777216u   // 256*256*256

typedef __attribute__((ext_vector_type(4))) float f4;
typedef __attribute__((ext_vector_type(4))) unsigned int u4;

// ws layout (bytes):
//   [0, 96 MB)        : fp16 transposed planes (3 x 32 MB), layout [hw][c=256]
//   +3.1 MB           : idx u32[3][NPTS]  (sorted pos -> original n)
//   +16.8 MB          : partial fp16[2][NPTS][16]  (planes 0,1 only)
//   +0.75 MB          : hist unsigned[3][65536]
#define OFF_IDX      (3ull * PLANE_ELEMS * 2ull)
#define OFF_PARTIAL  (OFF_IDX + (size_t)3 * NPTS * 4)
#define OFF_HIST     (OFF_PARTIAL + (size_t)2 * NPTS * 16 * 2)
#define WS_NEED      (OFF_HIST + (size_t)3 * 65536 * 4)

__device__ __forceinline__ void plane_xy(int p, float c0, float c1, float c2,
                                         float& gx, float& gy, float& ax) {
  if (p == 0)      { gx = c1; gy = c2; ax = c0; }
  else if (p == 1) { gx = c0; gy = c2; ax = c1; }
  else             { gx = c0; gy = c1; ax = c2; }
}

__device__ __forceinline__ int cell_of(float g) {
  float i = (g + 1.f) * 0.5f * 255.f;
  int x0 = (int)floorf(i);
  return x0 < 0 ? 0 : (x0 > 255 ? 255 : x0);
}

// ---------------------------------------------------------------------------
// Trans helpers (R10-verified).
// ---------------------------------------------------------------------------
__device__ __forceinline__ void trans_load(const float* __restrict__ src,
                                           unsigned c0, unsigned hw0, int tid,
                                           f4 (&va)[4], f4 (&vb)[4]) {
#pragma unroll
  for (int j = 0; j < 4; ++j) {
    int idx = j * 256 + tid;
    int rp = idx >> 5;
    int q = idx & 31;
    const f4* base = (const f4*)(src + (size_t)(c0 + 2 * rp) * 65536u + hw0 + 4 * q);
    va[j] = __builtin_nontemporal_load(base);
    vb[j] = __builtin_nontemporal_load(base + 16384);
  }
}

__device__ __forceinline__ void trans_proc(unsigned* tile, __half* dst,
                                           unsigned c0, unsigned hw0, int tid,
                                           f4 (&va)[4], f4 (&vb)[4]) {
#pragma unroll
  for (int j = 0; j < 4; ++j) {
    int idx = j * 256 + tid;
    int rp = idx >> 5;
    int q = idx & 31;
#pragma unroll
    for (int k = 0; k < 4; ++k) {
      int hw = 4 * q + k;
      __half2 h = __floats2half2_rn(va[j][k], vb[j][k]);
      tile[hw * 36 + (rp ^ (hw >> 3))] = *(unsigned*)&h;
    }
  }
  __syncthreads();
  int seg = tid & 7;
#pragma unroll
  for (int jj = 0; jj < 4; ++jj) {
    int hw = jj * 32 + (tid >> 3);
    int s = hw >> 3;
    u4 v = *(const u4*)(tile + hw * 36 + 4 * ((seg ^ (s >> 2)) & 7));
    u4 o;
    switch (s & 3) {
      case 0: o = v; break;
      case 1: o = u4{v.y, v.x, v.w, v.z}; break;
      case 2: o = u4{v.z, v.w, v.x, v.y}; break;
      default: o = u4{v.w, v.z, v.y, v.x}; break;
    }
    *(u4*)((char*)dst + ((size_t)(hw0 + hw) * 256u + c0) * 2u + seg * 16u) = o;
  }
  __syncthreads();
}

__device__ __forceinline__ void hist_point(
    int p, int n, const float* __restrict__ inputs, unsigned* __restrict__ hist) {
  float c0 = inputs[n * 3 + 0], c1 = inputs[n * 3 + 1], c2 = inputs[n * 3 + 2];
  float gx, gy, ax;
  plane_xy(p, c0, c1, c2, gx, gy, ax);
  int key = (cell_of(gy) << 8) | cell_of(gx);
  atomicAdd(&hist[p * 65536 + key], 1u);
}

__device__ __forceinline__ void scat_point(
    int p, int n, const float* __restrict__ inputs,
    unsigned* __restrict__ hist, unsigned* __restrict__ idx) {
  float c0 = inputs[n * 3 + 0], c1 = inputs[n * 3 + 1], c2 = inputs[n * 3 + 2];
  float gx, gy, ax;
  plane_xy(p, c0, c1, c2, gx, gy, ax);
  int key = (cell_of(gy) << 8) | cell_of(gx);
  unsigned pos = atomicAdd(&hist[p * 65536 + key], 1u);
  idx[(size_t)p * NPTS + pos] = (unsigned)n;
}

// ---------------------------------------------------------------------------
// Sample body (R12-verified). FINAL=1 fuses the reduce (R15).
// ---------------------------------------------------------------------------
template <int FINAL>
__device__ __forceinline__ void samp_point(
    int p, int slot, int t, const unsigned* __restrict__ idx,
    const float* __restrict__ inputs, const __half* __restrict__ T,
    __half* __restrict__ partial, float* __restrict__ out) {
  unsigned n = idx[(size_t)p * NPTS + slot];
  float c0 = inputs[n * 3 + 0], c1 = inputs[n * 3 + 1], c2 = inputs[n * 3 + 2];
  float gx, gy, ax;
  plane_xy(p, c0, c1, c2, gx, gy, ax);

  float ix = (gx + 1.f) * 0.5f * 255.f;
  float iy = (gy + 1.f) * 0.5f * 255.f;
  float x0f = floorf(ix), y0f = floorf(iy);
  float wx = ix - x0f, wy = iy - y0f;
  int x0 = (int)x0f; x0 = x0 < 0 ? 0 : (x0 > 255 ? 255 : x0);
  int y0 = (int)y0f; y0 = y0 < 0 ? 0 : (y0 > 255 ? 255 : y0);
  int x1 = x0 + 1 > 255 ? 255 : x0 + 1;
  int y1 = y0 + 1 > 255 ? 255 : y0 + 1;
  float w00 = (1.f - wx) * (1.f - wy);
  float w01 = wx * (1.f - wy);
  float w10 = (1.f - wx) * wy;
  float w11 = wx * wy;

  const __half* __restrict__ P = T + (size_t)p * PLANE_ELEMS;
  int r00 = (y0 * 256 + x0) * 256, r01 = (y0 * 256 + x1) * 256;
  int r10 = (y1 * 256 + x0) * 256, r11 = (y1 * 256 + x1) * 256;
  int ore = t * 16;
  int oim = 128 + t * 16;

  f4 a0 = *(const f4*)(P + r00 + ore),     a1 = *(const f4*)(P + r00 + ore + 8);
  f4 a2 = *(const f4*)(P + r00 + oim),     a3 = *(const f4*)(P + r00 + oim + 8);
  f4 b0 = *(const f4*)(P + r01 + ore),     b1 = *(const f4*)(P + r01 + ore + 8);
  f4 b2 = *(const f4*)(P + r01 + oim),     b3 = *(const f4*)(P + r01 + oim + 8);
  f4 c0v = *(const f4*)(P + r10 + ore),    c1v = *(const f4*)(P + r10 + ore + 8);
  f4 c2v = *(const f4*)(P + r10 + oim),    c3v = *(const f4*)(P + r10 + oim + 8);
  f4 d0 = *(const f4*)(P + r11 + ore),     d1 = *(const f4*)(P + r11 + ore + 8);
  f4 d2 = *(const f4*)(P + r11 + oim),     d3 = *(const f4*)(P + r11 + oim + 8);

  __half2 hw00 = __float2half2_rn(w00), hw01 = __float2half2_rn(w01);
  __half2 hw10 = __float2half2_rn(w10), hw11 = __float2half2_rn(w11);

  __half2 bre[8], bim[8];
#pragma unroll
  for (int q = 0; q < 4; ++q) {
    __half2 v;
    v = __hmul2(((const __half2*)&a0)[q], hw00);
    v = __hfma2(((const __half2*)&b0)[q],  hw01, v);
    v = __hfma2(((const __half2*)&c0v)[q], hw10, v);
    bre[q] = __hfma2(((const __half2*)&d0)[q], hw11, v);

    v = __hmul2(((const __half2*)&a1)[q], hw00);
    v = __hfma2(((const __half2*)&b1)[q],  hw01, v);
    v = __hfma2(((const __half2*)&c1v)[q], hw10, v);
    bre[q + 4] = __hfma2(((const __half2*)&d1)[q], hw11, v);

    v = __hmul2(((const __half2*)&a2)[q], hw00);
    v = __hfma2(((const __half2*)&b2)[q],  hw01, v);
    v = __hfma2(((const __half2*)&c2v)[q], hw10, v);
    bim[q] = __hfma2(((const __half2*)&d2)[q], hw11, v);

    v = __hmul2(((const __half2*)&a3)[q], hw00);
    v = __hfma2(((const __half2*)&b3)[q],  hw01, v);
    v = __hfma2(((const __half2*)&c3v)[q], hw10, v);
    bim[q + 4] = __hfma2(((const __half2*)&d3)[q], hw11, v);
  }

  float fre[16], fim[16];
#pragma unroll
  for (int q = 0; q < 8; ++q) {
    float2 vr = __half22float2(bre[q]);
    float2 vi = __half22float2(bim[q]);
    fre[2 * q] = vr.x; fre[2 * q + 1] = vr.y;
    fim[2 * q] = vi.x; fim[2 * q + 1] = vi.y;
  }

  float cs = (ax + 1.f) * 0.5f * 255.f;
  float th = 6.283185307179586f * cs * (1.f / 256.f);
  float s, c;
  __sincosf(th, &s, &c);
  float aR0 = fre[0], aR1 = fre[8];
  float aI0 = 0.f,    aI1 = 0.f;
#pragma unroll
  for (int r = 1; r < 8; ++r) {
    aR0 += fre[r] * c;     aR1 += fre[8 + r] * c;
    aI0 += fim[r] * s;     aI1 += fim[8 + r] * s;
    if (r < 7) {
      float c2 = c + c;
      float cn = c2 * c - 1.f;
      s = c2 * s;
      c = cn;
    }
  }

  if (FINAL) {
    const size_t PS = (size_t)NPTS * 16;
    float2 p0 = __half22float2(*(const __half2*)(partial + (size_t)n * 16 + 2 * t));
    float2 p1 = __half22float2(*(const __half2*)(partial + PS + (size_t)n * 16 + 2 * t));
    float2 o;
    o.x = (aR0 - aI0) + p0.x + p1.x;
    o.y = (aR1 - aI1) + p0.y + p1.y;
    *(float2*)(out + (size_t)n * 16 + 2 * t) = o;
  } else {
    *(__half2*)(partial + ((size_t)p * NPTS + n) * 16 + 2 * t) =
        __floats2half2_rn(aR0 - aI0, aR1 - aI1);
  }
}

// ---------------------------------------------------------------------------
// K1 fat kernel: trans ∥ hist, hist blocks interleaved (bx%3==2). [R14/R15]
// grid 2304, block 256.
// ---------------------------------------------------------------------------
__global__ __launch_bounds__(256) void PREFFFT_fat1_k(
    const float* __restrict__ Pu, const float* __restrict__ Pv,
    const float* __restrict__ Pw, __half* __restrict__ dst0,
    const float* __restrict__ inputs, unsigned* __restrict__ hist) {
  __shared__ unsigned tile[128 * 36];
  const int bx = blockIdx.x;
  const int tid = threadIdx.x;
  if ((bx % 3) != 2) {
    int ti = (bx / 3) * 2 + (bx % 3);   // 0..1535
    int bz = ti / 512;
    int rem = ti - bz * 512;
    int by = rem >> 7;
    int bxx = rem & 127;
    const float* src = bz == 0 ? Pu : (bz == 1 ? Pv : Pw);
    __half* dst = dst0 + (size_t)bz * PLANE_ELEMS;
    const unsigned hwbase = bxx * 512u;
    const unsigned c0 = by * 64u;
    f4 vaA[4], vbA[4], vaB[4], vbB[4];
    trans_load(src, c0, hwbase, tid, vaA, vbA);
    trans_load(src, c0, hwbase + 128u, tid, vaB, vbB);
    trans_proc(tile, dst, c0, hwbase, tid, vaA, vbA);
    trans_load(src, c0, hwbase + 256u, tid, vaA, vbA);
    trans_proc(tile, dst, c0, hwbase + 128u, tid, vaB, vbB);
    trans_load(src, c0, hwbase + 384u, tid, vaB, vbB);
    trans_proc(tile, dst, c0, hwbase + 256u, tid, vaA, vbA);
    trans_proc(tile, dst, c0, hwbase + 384u, tid, vaB, vbB);
  } else {
    int hb = bx / 3;                    // 0..767
#pragma unroll
    for (int it = 0; it < 4; ++it) {
      int item = hb * 1024 + it * 256 + tid;
      int n = item & (NPTS - 1);
      int p = item >> 18;
      hist_point(p, n, inputs, hist);
    }
  }
}

// ---------------------------------------------------------------------------
// Scan body: exclusive prefix over 65536 bins of plane p (1024 threads).
// ---------------------------------------------------------------------------
__device__ __forceinline__ void scan_plane(unsigned* __restrict__ hist, int p,
                                           unsigned* part, int t) {
  unsigned* h = hist + (size_t)p * 65536;
  unsigned s = 0;
#pragma unroll 8
  for (int i = 0; i < 64; ++i) s += h[t * 64 + i];
  part[t] = s;
  __syncthreads();
  for (int off = 1; off < 1024; off <<= 1) {
    unsigned v = (t >= off) ? part[t - off] : 0u;
    __syncthreads();
    part[t] += v;
    __syncthreads();
  }
  unsigned run = (t == 0) ? 0u : part[t - 1];
#pragma unroll 8
  for (int i = 0; i < 64; ++i) {
    unsigned c = h[t * 64 + i];
    h[t * 64 + i] = run;
    run += c;
  }
}

__global__ __launch_bounds__(1024) void PREFFFT_scan0_k(unsigned* __restrict__ hist) {
  __shared__ unsigned part[1024];
  scan_plane(hist, 0, part, threadIdx.x);
}

// ---------------------------------------------------------------------------
// Merged: blocks 0,1 = scan planes 1,2 (disjoint hist ranges); blocks 2..257
// = scat(plane 0), 1024 points each. Hides the p1/p2 scans under scat0.
// grid 258, block 1024.
// ---------------------------------------------------------------------------
__global__ __launch_bounds__(1024) void PREFFFT_scanscat_k(
    const float* __restrict__ inputs, unsigned* __restrict__ hist,
    unsigned* __restrict__ idx) {
  __shared__ unsigned part[1024];
  int bx = blockIdx.x;
  int t = threadIdx.x;
  if (bx < 2) {
    scan_plane(hist, 1 + bx, part, t);
  } else {
    int n = (bx - 2) * 1024 + t;
    scat_point(0, n, inputs, hist, idx);
  }
}

// ---------------------------------------------------------------------------
// Fat pipeline kernel: blocks [0,1024) = scat(plane sp+1) — dispatched first,
// latency hides under the 8192 samp(plane sp) blocks [1024, 9216). [R13/R15]
// ---------------------------------------------------------------------------
__global__ __launch_bounds__(256) void PREFFFT_fat2_k(
    unsigned* __restrict__ idx, const float* __restrict__ inputs,
    const __half* __restrict__ T, __half* __restrict__ partial,
    unsigned* __restrict__ hist, int sp) {
  int bx = blockIdx.x;
  if (bx < 1024) {
    int n = bx * 256 + threadIdx.x;
    scat_point(sp + 1, n, inputs, hist, idx);
  } else {
    int b = bx - 1024;                        // 0..8191
    int lbx = (b & 7) * 1024 + (b >> 3);      // XCD-contiguous chunks
    int slot = lbx * 32 + ((int)threadIdx.x >> 3);
    samp_point<0>(sp, slot, threadIdx.x & 7, idx, inputs, T, partial, nullptr);
  }
}

// ---------------------------------------------------------------------------
// Final fused pass: samp(plane 2) + reduce(partials 0,1) -> f32 out. [R15]
// grid 8192.
// ---------------------------------------------------------------------------
__global__ __launch_bounds__(256) void PREFFFT_samp2out_k(
    const unsigned* __restrict__ idx, const float* __restrict__ inputs,
    const __half* __restrict__ T, __half* __restrict__ partial,
    float* __restrict__ out) {
  int b = blockIdx.x;
  int lbx = (b & 7) * 1024 + (b >> 3);
  int slot = lbx * 32 + ((int)threadIdx.x >> 3);
  samp_point<1>(2, slot, threadIdx.x & 7, idx, inputs, T, partial, out);
}

// ---------------------------------------------------------------------------
// Fallback (ws too small): original (C,H,W) fp32 direct, slow but correct.
// ---------------------------------------------------------------------------
__global__ __launch_bounds__(256) void PREFFFT_fallback_k(
    const float* __restrict__ inputs, const float* __restrict__ Tu,
    const float* __restrict__ Tv, const float* __restrict__ Tw,
    float* __restrict__ out) {
  int gtid = blockIdx.x * 256 + threadIdx.x;
  int n = gtid >> 5;
  int t = threadIdx.x & 31;
  const bool is_re = t < 16;
  float c0 = inputs[n * 3 + 0], c1 = inputs[n * 3 + 1], c2 = inputs[n * 3 + 2];
  const float* PL[3] = {Tu, Tv, Tw};
  float acc = 0.f;
#pragma unroll
  for (int p = 0; p < 3; ++p) {
    float gx, gy, ax;
    plane_xy(p, c0, c1, c2, gx, gy, ax);
    float ix = (gx + 1.f) * 0.5f * 255.f;
    float iy = (gy + 1.f) * 0.5f * 255.f;
    float x0f = floorf(ix), y0f = floorf(iy);
    float wx = ix - x0f, wy = iy - y0f;
    int x0 = (int)x0f; x0 = x0 < 0 ? 0 : (x0 > 255 ? 255 : x0);
    int y0 = (int)y0f; y0 = y0 < 0 ? 0 : (y0 > 255 ? 255 : y0);
    int x1 = x0 + 1 > 255 ? 255 : x0 + 1;
    int y1 = y0 + 1 > 255 ? 255 : y0 + 1;
    float w00 = (1.f - wx) * (1.f - wy), w01 = wx * (1.f - wy);
    float w10 = (1.f - wx) * wy, w11 = wx * wy;
    int i00 = y0 * 256 + x0, i01 = y0 * 256 + x1;
    int i10 = y1 * 256 + x0, i11 = y1 * 256 + x1;
    float b[8];
#pragma unroll
    for (int j = 0; j < 8; ++j) {
      const float* base = PL[p] + (size_t)(t * 8 + j) * 65536u;
      b[j] = w00 * base[i00] + w01 * base[i01] + w10 * base[i10] + w11 * base[i11];
    }
    float csv = (ax + 1.f) * 0.5f * 255.f;
    float theta1 = 6.283185307179586f * csv * (1.f / 256.f);
    float partial = is_re ? b[0] : 0.f;
#pragma unroll
    for (int r = 1; r < 8; ++r) {
      float thr = theta1 * (float)(1 << (r - 1));
      float s, c;
      __sincosf(thr, &s, &c);
      partial += b[r] * (is_re ? c : s);
    }
    float other = __shfl_xor(partial, 16);
    acc += partial - other;
  }
  if (is_re) out[n * 16 + t] = acc;
}

extern "C" void kernel_launch(void* const* d_in, const int* in_sizes, int n_in,
                              void* d_out, int out_size, void* d_ws, size_t ws_size,
                              hipStream_t stream) {
  const float* inputs = (const float*)d_in[0];
  const float* Pu = (const float*)d_in[1];
  const float* Pv = (const float*)d_in[2];
  const float* Pw = (const float*)d_in[3];
  float* out = (float*)d_out;

  if (ws_size >= WS_NEED) {
    char* ws = (char*)d_ws;
    __half*   T       = (__half*)ws;
    unsigned* idx     = (unsigned*)(ws + OFF_IDX);
    __half*   partial = (__half*)(ws + OFF_PARTIAL);
    unsigned* hist    = (unsigned*)(ws + OFF_HIST);

    hipMemsetAsync(hist, 0, (size_t)3 * 65536 * 4, stream);
    PREFFFT_fat1_k<<<2304, 256, 0, stream>>>(Pu, Pv, Pw, T, inputs, hist);
    PREFFFT_scan0_k<<<1, 1024, 0, stream>>>(hist);
    PREFFFT_scanscat_k<<<258, 1024, 0, stream>>>(inputs, hist, idx);
    PREFFFT_fat2_k<<<9216, 256, 0, stream>>>(idx, inputs, T, partial, hist, 0);
    PREFFFT_fat2_k<<<9216, 256, 0, stream>>>(idx, inputs, T, partial, hist, 1);
    PREFFFT_samp2out_k<<<8192, 256, 0, stream>>>(idx, inputs, T, partial, out);
  } else {
    PREFFFT_fallback_k<<<NPTS / 8, 256, 0, stream>>>(inputs, Pu, Pv, Pw, out);
  }
}

// Round 18
// 194.860 us; speedup vs baseline: 1.1511x; 1.1148x over previous
//
#include <hip/hip_runtime.h>
#include <hip/hip_fp16.h>
#include <math.h>

#define NPTS 262144
#define PLANE_ELEMS 16777216u   // 256*256*256

typedef __attribute__((ext_vector_type(4))) float f4;
typedef __attribute__((ext_vector_type(4))) unsigned int u4;

// ws layout (bytes):
//   [0, 96 MB)        : fp16 transposed planes (3 x 32 MB), layout [hw][c=256]
//   +3.1 MB           : idx u32[3][NPTS]  (sorted pos -> original n)
//   +16.8 MB          : partial fp16[2][NPTS][16]  (planes 0,1 only)
//   +0.75 MB          : hist unsigned[3][65536]
#define OFF_IDX      (3ull * PLANE_ELEMS * 2ull)
#define OFF_PARTIAL  (OFF_IDX + (size_t)3 * NPTS * 4)
#define OFF_HIST     (OFF_PARTIAL + (size_t)2 * NPTS * 16 * 2)
#define WS_NEED      (OFF_HIST + (size_t)3 * 65536 * 4)

__device__ __forceinline__ void plane_xy(int p, float c0, float c1, float c2,
                                         float& gx, float& gy, float& ax) {
  if (p == 0)      { gx = c1; gy = c2; ax = c0; }
  else if (p == 1) { gx = c0; gy = c2; ax = c1; }
  else             { gx = c0; gy = c1; ax = c2; }
}

__device__ __forceinline__ int cell_of(float g) {
  float i = (g + 1.f) * 0.5f * 255.f;
  int x0 = (int)floorf(i);
  return x0 < 0 ? 0 : (x0 > 255 ? 255 : x0);
}

// ---------------------------------------------------------------------------
// Trans helpers (R10-verified).
// ---------------------------------------------------------------------------
__device__ __forceinline__ void trans_load(const float* __restrict__ src,
                                           unsigned c0, unsigned hw0, int tid,
                                           f4 (&va)[4], f4 (&vb)[4]) {
#pragma unroll
  for (int j = 0; j < 4; ++j) {
    int idx = j * 256 + tid;
    int rp = idx >> 5;
    int q = idx & 31;
    const f4* base = (const f4*)(src + (size_t)(c0 + 2 * rp) * 65536u + hw0 + 4 * q);
    va[j] = __builtin_nontemporal_load(base);
    vb[j] = __builtin_nontemporal_load(base + 16384);
  }
}

__device__ __forceinline__ void trans_proc(unsigned* tile, __half* dst,
                                           unsigned c0, unsigned hw0, int tid,
                                           f4 (&va)[4], f4 (&vb)[4]) {
#pragma unroll
  for (int j = 0; j < 4; ++j) {
    int idx = j * 256 + tid;
    int rp = idx >> 5;
    int q = idx & 31;
#pragma unroll
    for (int k = 0; k < 4; ++k) {
      int hw = 4 * q + k;
      __half2 h = __floats2half2_rn(va[j][k], vb[j][k]);
      tile[hw * 36 + (rp ^ (hw >> 3))] = *(unsigned*)&h;
    }
  }
  __syncthreads();
  int seg = tid & 7;
#pragma unroll
  for (int jj = 0; jj < 4; ++jj) {
    int hw = jj * 32 + (tid >> 3);
    int s = hw >> 3;
    u4 v = *(const u4*)(tile + hw * 36 + 4 * ((seg ^ (s >> 2)) & 7));
    u4 o;
    switch (s & 3) {
      case 0: o = v; break;
      case 1: o = u4{v.y, v.x, v.w, v.z}; break;
      case 2: o = u4{v.z, v.w, v.x, v.y}; break;
      default: o = u4{v.w, v.z, v.y, v.x}; break;
    }
    *(u4*)((char*)dst + ((size_t)(hw0 + hw) * 256u + c0) * 2u + seg * 16u) = o;
  }
  __syncthreads();
}

__device__ __forceinline__ void hist_point(
    int p, int n, const float* __restrict__ inputs, unsigned* __restrict__ hist) {
  float c0 = inputs[n * 3 + 0], c1 = inputs[n * 3 + 1], c2 = inputs[n * 3 + 2];
  float gx, gy, ax;
  plane_xy(p, c0, c1, c2, gx, gy, ax);
  int key = (cell_of(gy) << 8) | cell_of(gx);
  atomicAdd(&hist[p * 65536 + key], 1u);
}

__device__ __forceinline__ void scat_point(
    int p, int n, const float* __restrict__ inputs,
    unsigned* __restrict__ hist, unsigned* __restrict__ idx) {
  float c0 = inputs[n * 3 + 0], c1 = inputs[n * 3 + 1], c2 = inputs[n * 3 + 2];
  float gx, gy, ax;
  plane_xy(p, c0, c1, c2, gx, gy, ax);
  int key = (cell_of(gy) << 8) | cell_of(gx);
  unsigned pos = atomicAdd(&hist[p * 65536 + key], 1u);
  idx[(size_t)p * NPTS + pos] = (unsigned)n;
}

// ---------------------------------------------------------------------------
// Sample body (R12-verified). FINAL=1 fuses the reduce (R15).
// ---------------------------------------------------------------------------
template <int FINAL>
__device__ __forceinline__ void samp_point(
    int p, int slot, int t, const unsigned* __restrict__ idx,
    const float* __restrict__ inputs, const __half* __restrict__ T,
    __half* __restrict__ partial, float* __restrict__ out) {
  unsigned n = idx[(size_t)p * NPTS + slot];
  float c0 = inputs[n * 3 + 0], c1 = inputs[n * 3 + 1], c2 = inputs[n * 3 + 2];
  float gx, gy, ax;
  plane_xy(p, c0, c1, c2, gx, gy, ax);

  float ix = (gx + 1.f) * 0.5f * 255.f;
  float iy = (gy + 1.f) * 0.5f * 255.f;
  float x0f = floorf(ix), y0f = floorf(iy);
  float wx = ix - x0f, wy = iy - y0f;
  int x0 = (int)x0f; x0 = x0 < 0 ? 0 : (x0 > 255 ? 255 : x0);
  int y0 = (int)y0f; y0 = y0 < 0 ? 0 : (y0 > 255 ? 255 : y0);
  int x1 = x0 + 1 > 255 ? 255 : x0 + 1;
  int y1 = y0 + 1 > 255 ? 255 : y0 + 1;
  float w00 = (1.f - wx) * (1.f - wy);
  float w01 = wx * (1.f - wy);
  float w10 = (1.f - wx) * wy;
  float w11 = wx * wy;

  const __half* __restrict__ P = T + (size_t)p * PLANE_ELEMS;
  int r00 = (y0 * 256 + x0) * 256, r01 = (y0 * 256 + x1) * 256;
  int r10 = (y1 * 256 + x0) * 256, r11 = (y1 * 256 + x1) * 256;
  int ore = t * 16;
  int oim = 128 + t * 16;

  f4 a0 = *(const f4*)(P + r00 + ore),     a1 = *(const f4*)(P + r00 + ore + 8);
  f4 a2 = *(const f4*)(P + r00 + oim),     a3 = *(const f4*)(P + r00 + oim + 8);
  f4 b0 = *(const f4*)(P + r01 + ore),     b1 = *(const f4*)(P + r01 + ore + 8);
  f4 b2 = *(const f4*)(P + r01 + oim),     b3 = *(const f4*)(P + r01 + oim + 8);
  f4 c0v = *(const f4*)(P + r10 + ore),    c1v = *(const f4*)(P + r10 + ore + 8);
  f4 c2v = *(const f4*)(P + r10 + oim),    c3v = *(const f4*)(P + r10 + oim + 8);
  f4 d0 = *(const f4*)(P + r11 + ore),     d1 = *(const f4*)(P + r11 + ore + 8);
  f4 d2 = *(const f4*)(P + r11 + oim),     d3 = *(const f4*)(P + r11 + oim + 8);

  __half2 hw00 = __float2half2_rn(w00), hw01 = __float2half2_rn(w01);
  __half2 hw10 = __float2half2_rn(w10), hw11 = __float2half2_rn(w11);

  __half2 bre[8], bim[8];
#pragma unroll
  for (int q = 0; q < 4; ++q) {
    __half2 v;
    v = __hmul2(((const __half2*)&a0)[q], hw00);
    v = __hfma2(((const __half2*)&b0)[q],  hw01, v);
    v = __hfma2(((const __half2*)&c0v)[q], hw10, v);
    bre[q] = __hfma2(((const __half2*)&d0)[q], hw11, v);

    v = __hmul2(((const __half2*)&a1)[q], hw00);
    v = __hfma2(((const __half2*)&b1)[q],  hw01, v);
    v = __hfma2(((const __half2*)&c1v)[q], hw10, v);
    bre[q + 4] = __hfma2(((const __half2*)&d1)[q], hw11, v);

    v = __hmul2(((const __half2*)&a2)[q], hw00);
    v = __hfma2(((const __half2*)&b2)[q],  hw01, v);
    v = __hfma2(((const __half2*)&c2v)[q], hw10, v);
    bim[q] = __hfma2(((const __half2*)&d2)[q], hw11, v);

    v = __hmul2(((const __half2*)&a3)[q], hw00);
    v = __hfma2(((const __half2*)&b3)[q],  hw01, v);
    v = __hfma2(((const __half2*)&c3v)[q], hw10, v);
    bim[q + 4] = __hfma2(((const __half2*)&d3)[q], hw11, v);
  }

  float fre[16], fim[16];
#pragma unroll
  for (int q = 0; q < 8; ++q) {
    float2 vr = __half22float2(bre[q]);
    float2 vi = __half22float2(bim[q]);
    fre[2 * q] = vr.x; fre[2 * q + 1] = vr.y;
    fim[2 * q] = vi.x; fim[2 * q + 1] = vi.y;
  }

  float cs = (ax + 1.f) * 0.5f * 255.f;
  float th = 6.283185307179586f * cs * (1.f / 256.f);
  float s, c;
  __sincosf(th, &s, &c);
  float aR0 = fre[0], aR1 = fre[8];
  float aI0 = 0.f,    aI1 = 0.f;
#pragma unroll
  for (int r = 1; r < 8; ++r) {
    aR0 += fre[r] * c;     aR1 += fre[8 + r] * c;
    aI0 += fim[r] * s;     aI1 += fim[8 + r] * s;
    if (r < 7) {
      float c2 = c + c;
      float cn = c2 * c - 1.f;
      s = c2 * s;
      c = cn;
    }
  }

  if (FINAL) {
    const size_t PS = (size_t)NPTS * 16;
    float2 p0 = __half22float2(*(const __half2*)(partial + (size_t)n * 16 + 2 * t));
    float2 p1 = __half22float2(*(const __half2*)(partial + PS + (size_t)n * 16 + 2 * t));
    float2 o;
    o.x = (aR0 - aI0) + p0.x + p1.x;
    o.y = (aR1 - aI1) + p0.y + p1.y;
    *(float2*)(out + (size_t)n * 16 + 2 * t) = o;
  } else {
    *(__half2*)(partial + ((size_t)p * NPTS + n) * 16 + 2 * t) =
        __floats2half2_rn(aR0 - aI0, aR1 - aI1);
  }
}

// ---------------------------------------------------------------------------
// K1 fat kernel: trans ∥ hist, hist blocks interleaved (bx%3==2). [R14]
// grid 2304, block 256.
// ---------------------------------------------------------------------------
__global__ __launch_bounds__(256) void PREFFFT_fat1_k(
    const float* __restrict__ Pu, const float* __restrict__ Pv,
    const float* __restrict__ Pw, __half* __restrict__ dst0,
    const float* __restrict__ inputs, unsigned* __restrict__ hist) {
  __shared__ unsigned tile[128 * 36];
  const int bx = blockIdx.x;
  const int tid = threadIdx.x;
  if ((bx % 3) != 2) {
    int ti = (bx / 3) * 2 + (bx % 3);   // 0..1535
    int bz = ti / 512;
    int rem = ti - bz * 512;
    int by = rem >> 7;
    int bxx = rem & 127;
    const float* src = bz == 0 ? Pu : (bz == 1 ? Pv : Pw);
    __half* dst = dst0 + (size_t)bz * PLANE_ELEMS;
    const unsigned hwbase = bxx * 512u;
    const unsigned c0 = by * 64u;
    f4 vaA[4], vbA[4], vaB[4], vbB[4];
    trans_load(src, c0, hwbase, tid, vaA, vbA);
    trans_load(src, c0, hwbase + 128u, tid, vaB, vbB);
    trans_proc(tile, dst, c0, hwbase, tid, vaA, vbA);
    trans_load(src, c0, hwbase + 256u, tid, vaA, vbA);
    trans_proc(tile, dst, c0, hwbase + 128u, tid, vaB, vbB);
    trans_load(src, c0, hwbase + 384u, tid, vaB, vbB);
    trans_proc(tile, dst, c0, hwbase + 256u, tid, vaA, vbA);
    trans_proc(tile, dst, c0, hwbase + 384u, tid, vaB, vbB);
  } else {
    int hb = bx / 3;                    // 0..767
#pragma unroll
    for (int it = 0; it < 4; ++it) {
      int item = hb * 1024 + it * 256 + tid;
      int n = item & (NPTS - 1);
      int p = item >> 18;
      hist_point(p, n, inputs, hist);
    }
  }
}

// ---------------------------------------------------------------------------
// Scan: exclusive prefix over 65536 bins; one block per plane.
// ---------------------------------------------------------------------------
__global__ __launch_bounds__(1024) void PREFFFT_scan_k(unsigned* __restrict__ hist) {
  __shared__ unsigned part[1024];
  unsigned* h = hist + (size_t)blockIdx.x * 65536;
  int t = threadIdx.x;
  unsigned s = 0;
#pragma unroll 8
  for (int i = 0; i < 64; ++i) s += h[t * 64 + i];
  part[t] = s;
  __syncthreads();
  for (int off = 1; off < 1024; off <<= 1) {
    unsigned v = (t >= off) ? part[t - off] : 0u;
    __syncthreads();
    part[t] += v;
    __syncthreads();
  }
  unsigned run = (t == 0) ? 0u : part[t - 1];
#pragma unroll 8
  for (int i = 0; i < 64; ++i) {
    unsigned c = h[t * 64 + i];
    h[t * 64 + i] = run;
    run += c;
  }
}

// ---------------------------------------------------------------------------
// Standalone scatter for plane 0 (the only latency-exposed one).
// ---------------------------------------------------------------------------
__global__ __launch_bounds__(256) void PREFFFT_scat1_k(
    const float* __restrict__ inputs, unsigned* __restrict__ hist,
    unsigned* __restrict__ idx) {
  int n = blockIdx.x * 256 + threadIdx.x;
  scat_point(0, n, inputs, hist, idx);
}

// ---------------------------------------------------------------------------
// Fat pipeline kernel: blocks [0,1024) = scat(plane sp+1) — dispatched first,
// latency hides under the 8192 samp(plane sp) blocks [1024, 9216).
// ---------------------------------------------------------------------------
__global__ __launch_bounds__(256) void PREFFFT_fat2_k(
    unsigned* __restrict__ idx, const float* __restrict__ inputs,
    const __half* __restrict__ T, __half* __restrict__ partial,
    unsigned* __restrict__ hist, int sp) {
  int bx = blockIdx.x;
  if (bx < 1024) {
    int n = bx * 256 + threadIdx.x;
    scat_point(sp + 1, n, inputs, hist, idx);
  } else {
    int b = bx - 1024;                        // 0..8191
    int lbx = (b & 7) * 1024 + (b >> 3);      // XCD-contiguous chunks
    int slot = lbx * 32 + ((int)threadIdx.x >> 3);
    samp_point<0>(sp, slot, threadIdx.x & 7, idx, inputs, T, partial, nullptr);
  }
}

// ---------------------------------------------------------------------------
// Final fused pass: samp(plane 2) + reduce(partials 0,1) -> f32 out. grid 8192.
// ---------------------------------------------------------------------------
__global__ __launch_bounds__(256) void PREFFFT_samp2out_k(
    const unsigned* __restrict__ idx, const float* __restrict__ inputs,
    const __half* __restrict__ T, __half* __restrict__ partial,
    float* __restrict__ out) {
  int b = blockIdx.x;
  int lbx = (b & 7) * 1024 + (b >> 3);
  int slot = lbx * 32 + ((int)threadIdx.x >> 3);
  samp_point<1>(2, slot, threadIdx.x & 7, idx, inputs, T, partial, out);
}

// ---------------------------------------------------------------------------
// Fallback (ws too small): original (C,H,W) fp32 direct, slow but correct.
// ---------------------------------------------------------------------------
__global__ __launch_bounds__(256) void PREFFFT_fallback_k(
    const float* __restrict__ inputs, const float* __restrict__ Tu,
    const float* __restrict__ Tv, const float* __restrict__ Tw,
    float* __restrict__ out) {
  int gtid = blockIdx.x * 256 + threadIdx.x;
  int n = gtid >> 5;
  int t = threadIdx.x & 31;
  const bool is_re = t < 16;
  float c0 = inputs[n * 3 + 0], c1 = inputs[n * 3 + 1], c2 = inputs[n * 3 + 2];
  const float* PL[3] = {Tu, Tv, Tw};
  float acc = 0.f;
#pragma unroll
  for (int p = 0; p < 3; ++p) {
    float gx, gy, ax;
    plane_xy(p, c0, c1, c2, gx, gy, ax);
    float ix = (gx + 1.f) * 0.5f * 255.f;
    float iy = (gy + 1.f) * 0.5f * 255.f;
    float x0f = floorf(ix), y0f = floorf(iy);
    float wx = ix - x0f, wy = iy - y0f;
    int x0 = (int)x0f; x0 = x0 < 0 ? 0 : (x0 > 255 ? 255 : x0);
    int y0 = (int)y0f; y0 = y0 < 0 ? 0 : (y0 > 255 ? 255 : y0);
    int x1 = x0 + 1 > 255 ? 255 : x0 + 1;
    int y1 = y0 + 1 > 255 ? 255 : y0 + 1;
    float w00 = (1.f - wx) * (1.f - wy), w01 = wx * (1.f - wy);
    float w10 = (1.f - wx) * wy, w11 = wx * wy;
    int i00 = y0 * 256 + x0, i01 = y0 * 256 + x1;
    int i10 = y1 * 256 + x0, i11 = y1 * 256 + x1;
    float b[8];
#pragma unroll
    for (int j = 0; j < 8; ++j) {
      const float* base = PL[p] + (size_t)(t * 8 + j) * 65536u;
      b[j] = w00 * base[i00] + w01 * base[i01] + w10 * base[i10] + w11 * base[i11];
    }
    float csv = (ax + 1.f) * 0.5f * 255.f;
    float theta1 = 6.283185307179586f * csv * (1.f / 256.f);
    float partial = is_re ? b[0] : 0.f;
#pragma unroll
    for (int r = 1; r < 8; ++r) {
      float thr = theta1 * (float)(1 << (r - 1));
      float s, c;
      __sincosf(thr, &s, &c);
      partial += b[r] * (is_re ? c : s);
    }
    float other = __shfl_xor(partial, 16);
    acc += partial - other;
  }
  if (is_re) out[n * 16 + t] = acc;
}

extern "C" void kernel_launch(void* const* d_in, const int* in_sizes, int n_in,
                              void* d_out, int out_size, void* d_ws, size_t ws_size,
                              hipStream_t stream) {
  const float* inputs = (const float*)d_in[0];
  const float* Pu = (const float*)d_in[1];
  const float* Pv = (const float*)d_in[2];
  const float* Pw = (const float*)d_in[3];
  float* out = (float*)d_out;

  if (ws_size >= WS_NEED) {
    char* ws = (char*)d_ws;
    __half*   T       = (__half*)ws;
    unsigned* idx     = (unsigned*)(ws + OFF_IDX);
    __half*   partial = (__half*)(ws + OFF_PARTIAL);
    unsigned* hist    = (unsigned*)(ws + OFF_HIST);

    hipMemsetAsync(hist, 0, (size_t)3 * 65536 * 4, stream);
    PREFFFT_fat1_k<<<2304, 256, 0, stream>>>(Pu, Pv, Pw, T, inputs, hist);
    PREFFFT_scan_k<<<3, 1024, 0, stream>>>(hist);
    PREFFFT_scat1_k<<<1024, 256, 0, stream>>>(inputs, hist, idx);
    PREFFFT_fat2_k<<<9216, 256, 0, stream>>>(idx, inputs, T, partial, hist, 0);
    PREFFFT_fat2_k<<<9216, 256, 0, stream>>>(idx, inputs, T, partial, hist, 1);
    PREFFFT_samp2out_k<<<8192, 256, 0, stream>>>(idx, inputs, T, partial, out);
  } else {
    PREFFFT_fallback_k<<<NPTS / 8, 256, 0, stream>>>(inputs, Pu, Pv, Pw, out);
  }
}